// Round 6
// baseline (228.995 us; speedup 1.0000x reference)
//
#include <hip/hip_runtime.h>
#include <stdint.h>

// ---- problem constants ----
constexpr int NBASES = 32;
constexpr int NKP    = 17;
constexpr int HDIM   = 100, WDIM = 152;
constexpr int HW     = HDIM * WDIM;       // 15200
constexpr int NI     = 64;
constexpr int KF     = 2304;
constexpr int AL     = 2737;
constexpr int ALP    = 2740;              // padded per-instance stride (16B-aligned rows)
// packed reference offsets inside an attns row
constexpr int OB0 = 1088;
constexpr int OW1 = 1120;
constexpr int OB1 = 2144;
constexpr int OW2 = 2176;
constexpr int OB2 = 2720;
// permuted layout (w0/w1 c-major; w2 k-major)
constexpr int TW0 = 0;      // [34][32]
constexpr int TB0 = 1088;   // 32
constexpr int TW1 = 1120;   // [32][32]
constexpr int TB1 = 2144;   // 32
constexpr int TW2 = 2176;   // [17][32]
constexpr int TB2 = 2720;   // 17

constexpr int PXB = 256;                     // pixels per block (256 thr x 1 px)
constexpr int NBX = (HW + PXB - 1) / PXB;    // 60

// gemm tiling
constexpr int JT     = 64;
constexpr int KCH    = 64;
constexpr int KSPLIT = 9;              // KT = 256 -> 387 blocks; keeps ws under budget
constexpr int KT     = KF / KSPLIT;
constexpr int NJT    = (AL + JT - 1) / JT;  // 43
constexpr int JTOT   = NJT * JT;            // 2752
constexpr int LPAD   = 68;

// ws layout (bytes): 701,440 + 522,240 + 6,340,608 = 7,564,288 (< prior 9.42 MB)
constexpr size_t ATT_OFF   = 0;                                  // NI*ALP*4
constexpr size_t ARGP_OFF  = (size_t)NI * ALP * 4;
constexpr size_t GEMMP_OFF = ARGP_OFF + (size_t)NI * NKP * NBX * 8;

__device__ __forceinline__ int perm(int j) {
    if (j < OB0)      { int o = j / 34, c = j - o * 34; return TW0 + c * 32 + o; }
    else if (j < OW1) return TB0 + (j - OB0);
    else if (j < OB1) { int q = j - OW1; int o = q >> 5, c = q & 31; return TW1 + c * 32 + o; }
    else if (j < OW2) return TB1 + (j - OB1);
    else if (j < OB2) return TW2 + (j - OW2);
    else              return TB2 + (j - OB2);
}

// ========== kernel 1: attns GEMM partials (no atomics) ==========
__global__ __launch_bounds__(256) void gemm_attn(const float* __restrict__ tf,
                                                 const float* __restrict__ W,
                                                 float* __restrict__ partial) {
    __shared__ __align__(16) float Tl[KCH][LPAD];
    __shared__ __align__(16) float Wl[KCH][LPAD];
    int jb = blockIdx.x % NJT;
    int ks = blockIdx.x / NJT;
    int j0 = jb * JT;
    int k0 = ks * KT;
    int tid = threadIdx.x;
    int tn = tid % 16;
    int tj = tid / 16;
    int lk = tid % 64;
    int lr = tid / 64;
    float acc[4][4] = {};
    for (int kc = 0; kc < KT; kc += KCH) {
        int kbase = k0 + kc;
        #pragma unroll
        for (int i = 0; i < 16; i++) {
            int nn = lr * 16 + i;
            Tl[lk][nn] = tf[(size_t)nn * KF + kbase + lk];
        }
        #pragma unroll
        for (int i = 0; i < 16; i++) {
            int j = j0 + lr * 16 + i;
            Wl[lk][lr * 16 + i] = (j < AL) ? W[(size_t)j * KF + kbase + lk] : 0.0f;
        }
        __syncthreads();
        #pragma unroll 4
        for (int kk = 0; kk < KCH; ++kk) {
            float tv[4], wv[4];
            #pragma unroll
            for (int i = 0; i < 4; i++) tv[i] = Tl[kk][tn * 4 + i];
            #pragma unroll
            for (int i = 0; i < 4; i++) wv[i] = Wl[kk][tj * 4 + i];
            #pragma unroll
            for (int i = 0; i < 4; i++)
                #pragma unroll
                for (int q = 0; q < 4; q++) acc[i][q] += tv[i] * wv[q];
        }
        __syncthreads();
    }
    // plain stores to disjoint per-ks partials (float4, 16B-aligned)
    size_t pbase = (size_t)(ks * NI) * JTOT;
    #pragma unroll
    for (int i = 0; i < 4; i++) {
        int nn = tn * 4 + i;
        int j = j0 + tj * 4;
        float4 st = make_float4(acc[i][0], acc[i][1], acc[i][2], acc[i][3]);
        *(float4*)&partial[pbase + (size_t)nn * JTOT + j] = st;
    }
}

// ========== kernel 2: reduce partials + bias -> permuted att_p ==========
__global__ __launch_bounds__(256) void reduce_attn(const float* __restrict__ partial,
                                                   const float* __restrict__ b,
                                                   float* __restrict__ att_p) {
    int n = blockIdx.y;
    int j = blockIdx.x * 256 + threadIdx.x;
    if (j >= AL) return;
    float s = b[j];
    #pragma unroll
    for (int ks = 0; ks < KSPLIT; ks++)
        s += partial[(size_t)(ks * NI + n) * JTOT + j];
    att_p[(size_t)n * ALP + perm(j)] = s;
}

// ========== kernel 3: fused per-pixel head + block argmax ==========
// All weights are block-uniform (depend only on n = blockIdx.y) -> read them
// through the uniform global pointer so the compiler scalarizes to s_load and
// folds SGPR operands straight into v_fmac. Zero LDS / zero VMEM for weights.
// SGPR budget is the binding occupancy resource (~112 needed): do NOT request
// more than 6 waves/SIMD or the compiler spills WEIGHTS to scratch (round-3:
// (512,8) capped SGPR at 100 -> +211 MB scratch traffic, 104 -> 115 us).
// 256-thread blocks (4 waves) pack wave slots finer than 8-wave blocks and
// halve the drain-tail quantum on the grid.
__device__ inline unsigned int mono_f32(float f) {
    unsigned int u = __float_as_uint(f);
    return (u & 0x80000000u) ? ~u : (u | 0x80000000u);
}

__global__ __launch_bounds__(256, 6) void pixel_head(const float* __restrict__ bases_full,
                                                     const float* __restrict__ att_p,
                                                     const float* __restrict__ locations,
                                                     const float* __restrict__ soi,
                                                     const int* __restrict__ fpn,
                                                     float* __restrict__ out_logits,
                                                     unsigned long long* __restrict__ partial) {
    __shared__ unsigned long long red[4][NKP];
    int n = blockIdx.y, bx = blockIdx.x, tid = threadIdx.x;
    const float* wn = att_p + (size_t)n * ALP;       // block-uniform base

    int p0 = bx * PXB + tid;
    bool valid = p0 < HW;
    int pc = valid ? p0 : 0;
    int y = pc / WDIM, x = pc - y * WDIM;

    float inv = 1.0f / soi[fpn[n]];
    float lx = locations[2 * n], ly = locations[2 * n + 1];
    float cx = (lx - (float)(x * 8 + 4)) * inv;
    float cy = (ly - (float)(y * 8 + 4)) * inv;

    // issue first bases loads early so latency hides under the offsets FMAs
    const float* bp = bases_full + pc;
    float q0 = bp[0], q1 = bp[HW], q2 = bp[2 * (size_t)HW], q3 = bp[3 * (size_t)HW];

    // ---- layer 0: h = relu(W0 x + b0), c-outer streaming, scalar weights ----
    float h[32];
    {
        const float4* br  = (const float4*)(wn + TB0);
        const float4* w0r = (const float4*)(wn + TW0);
        const float4* w1r = (const float4*)(wn + TW0 + 32);
        #pragma unroll
        for (int g = 0; g < 8; g++) {
            float4 b4 = br[g], wv = w0r[g], wu = w1r[g];
            h[4*g+0] = b4.x + wv.x * cx + wu.x * cy;
            h[4*g+1] = b4.y + wv.y * cx + wu.y * cy;
            h[4*g+2] = b4.z + wv.z * cx + wu.z * cy;
            h[4*g+3] = b4.w + wv.w * cx + wu.w * cy;
        }
    }
    // 4-deep rolling prefetch over the 32 bases channels
    #pragma unroll 2
    for (int c0 = 0; c0 < 32; c0 += 4) {
        float n0 = 0.f, n1 = 0.f, n2 = 0.f, n3 = 0.f;
        if (c0 + 4 < 32) {
            n0 = bp[(size_t)(c0 + 4) * HW];
            n1 = bp[(size_t)(c0 + 5) * HW];
            n2 = bp[(size_t)(c0 + 6) * HW];
            n3 = bp[(size_t)(c0 + 7) * HW];
        }
        float qq[4] = {q0, q1, q2, q3};
        #pragma unroll
        for (int u = 0; u < 4; u++) {
            float bv = qq[u];
            const float4* wr = (const float4*)(wn + TW0 + (c0 + u + 2) * 32);
            #pragma unroll
            for (int g = 0; g < 8; g++) {
                float4 wv = wr[g];
                h[4*g+0] += wv.x * bv;
                h[4*g+1] += wv.y * bv;
                h[4*g+2] += wv.z * bv;
                h[4*g+3] += wv.w * bv;
            }
        }
        q0 = n0; q1 = n1; q2 = n2; q3 = n3;
    }
    #pragma unroll
    for (int o = 0; o < 32; o++) h[o] = fmaxf(h[o], 0.0f);

    // ---- layer 1: scalar weights via uniform global pointer ----
    float gg[32];
    {
        const float4* br = (const float4*)(wn + TB1);
        #pragma unroll
        for (int g = 0; g < 8; g++) {
            float4 b4 = br[g];
            gg[4*g+0] = b4.x; gg[4*g+1] = b4.y; gg[4*g+2] = b4.z; gg[4*g+3] = b4.w;
        }
    }
    #pragma unroll 4
    for (int c = 0; c < 32; c++) {
        float xv = h[c];
        const float4* wr = (const float4*)(wn + TW1 + c * 32);
        #pragma unroll
        for (int g = 0; g < 8; g++) {
            float4 wv = wr[g];
            gg[4*g+0] += wv.x * xv;
            gg[4*g+1] += wv.y * xv;
            gg[4*g+2] += wv.z * xv;
            gg[4*g+3] += wv.w * xv;
        }
    }
    #pragma unroll
    for (int o = 0; o < 32; o++) gg[o] = fmaxf(gg[o], 0.0f);

    // ---- layer 2: scalar weights; store logits + fused per-k argmax ----
    // Wave argmax: 32-bit fp max butterfly, then ballot + ffs for the winning
    // lane (lowest lane = smallest pixel index = numpy first-occurrence).
    size_t obase = (size_t)n * NKP * HW;
    int wid = tid >> 6, lane = tid & 63;
    #pragma unroll
    for (int k = 0; k < NKP; k++) {
        const float4* wr = (const float4*)(wn + TW2 + k * 32);
        float s = wn[TB2 + k];
        #pragma unroll
        for (int g = 0; g < 8; g++) {
            float4 wv = wr[g];
            s += wv.x * gg[4*g+0] + wv.y * gg[4*g+1] + wv.z * gg[4*g+2] + wv.w * gg[4*g+3];
        }
        if (valid)
            __builtin_nontemporal_store(s, &out_logits[obase + (size_t)k * HW + p0]);
        float sm = valid ? s : -__builtin_inff();
        float m = sm;
        #pragma unroll
        for (int off = 32; off > 0; off >>= 1)
            m = fmaxf(m, __shfl_xor(m, off));
        unsigned long long ball = __ballot(sm == m);
        if (lane == 0) {
            int winlane = __ffsll((unsigned long long)ball) - 1;
            unsigned pix = (unsigned)(bx * PXB + (wid << 6) + winlane);
            red[wid][k] = ((unsigned long long)mono_f32(m) << 32) |
                          (unsigned long long)(0xFFFFFFFFu - pix);
        }
    }
    __syncthreads();
    if (tid < NKP) {
        unsigned long long m = red[0][tid];
        #pragma unroll
        for (int ww = 1; ww < 4; ww++)
            if (red[ww][tid] > m) m = red[ww][tid];
        partial[((size_t)n * NKP + tid) * NBX + bx] = m;
    }
}

// ========== kernel 4: final argmax reduce + keypoint ==========
__global__ __launch_bounds__(64) void kp_final(const unsigned long long* __restrict__ partial,
                                               const float* __restrict__ bases_full,
                                               float* __restrict__ kp_out) {
    int b = blockIdx.x;
    int n = b / NKP, k = b % NKP;
    int lane = threadIdx.x;
    unsigned long long v = (lane < NBX) ? partial[((size_t)n * NKP + k) * NBX + lane] : 0ull;
    #pragma unroll
    for (int off = 32; off > 0; off >>= 1) {
        unsigned long long o = __shfl_down(v, off);
        if (o > v) v = o;
    }
    if (lane == 0) {
        int p = (int)(0xFFFFFFFFu - (unsigned)(v & 0xFFFFFFFFull));
        int yy = p / WDIM;
        int xx = p - yy * WDIM;
        float kx = bases_full[(size_t)(NBASES + 2 * k) * HW + p] + (float)(xx * 8 + 4);
        float ky = bases_full[(size_t)(NBASES + 2 * k + 1) * HW + p] + (float)(yy * 8 + 4);
        kp_out[((size_t)n * NKP + k) * 2 + 0] = kx;
        kp_out[((size_t)n * NKP + k) * 2 + 1] = ky;
    }
}

extern "C" void kernel_launch(void* const* d_in, const int* in_sizes, int n_in,
                              void* d_out, int out_size, void* d_ws, size_t ws_size,
                              hipStream_t stream) {
    const float* bases_full = (const float*)d_in[0];
    const float* top_feats  = (const float*)d_in[1];
    const float* locations  = (const float*)d_in[2];
    const float* atten_W    = (const float*)d_in[3];
    const float* atten_b    = (const float*)d_in[4];
    const float* soi        = (const float*)d_in[5];
    const int*   fpn        = (const int*)d_in[6];
    float* out   = (float*)d_out;
    float* att_p = (float*)((char*)d_ws + ATT_OFF);
    unsigned long long* argp = (unsigned long long*)((char*)d_ws + ARGP_OFF);
    float* gemmp = (float*)((char*)d_ws + GEMMP_OFF);

    gemm_attn<<<NJT * KSPLIT, 256, 0, stream>>>(top_feats, atten_W, gemmp);

    dim3 gr((AL + 255) / 256, NI);   // 11 x 64
    reduce_attn<<<gr, 256, 0, stream>>>(gemmp, atten_b, att_p);

    dim3 g2(NBX, NI);   // 60 x 64
    pixel_head<<<g2, 256, 0, stream>>>(bases_full, att_p, locations, soi, fpn, out, argp);

    float* kp_out = out + (size_t)NI * NKP * HW;
    kp_final<<<NI * NKP, 64, 0, stream>>>(argp, bases_full, kp_out);
}

// Round 7
// 218.695 us; speedup vs baseline: 1.0471x; 1.0471x over previous
//
#include <hip/hip_runtime.h>
#include <stdint.h>

// ---- problem constants ----
constexpr int NBASES = 32;
constexpr int NKP    = 17;
constexpr int HDIM   = 100, WDIM = 152;
constexpr int HW     = HDIM * WDIM;       // 15200
constexpr int NI     = 64;
constexpr int KF     = 2304;
constexpr int AL     = 2737;
constexpr int ALP    = 2740;              // padded per-instance stride (16B-aligned rows)
// packed reference offsets inside an attns row
constexpr int OB0 = 1088;
constexpr int OW1 = 1120;
constexpr int OB1 = 2144;
constexpr int OW2 = 2176;
constexpr int OB2 = 2720;
// permuted layout (w0/w1 c-major; w2 k-major)
constexpr int TW0 = 0;      // [34][32]
constexpr int TB0 = 1088;   // 32
constexpr int TW1 = 1120;   // [32][32]
constexpr int TB1 = 2144;   // 32
constexpr int TW2 = 2176;   // [17][32]
constexpr int TB2 = 2720;   // 17

constexpr int PXB = 256;                     // pixels per block (256 thr x 1 px)
constexpr int NBX = (HW + PXB - 1) / PXB;    // 60

// gemm tiling
constexpr int JT     = 64;
constexpr int KCH    = 64;
constexpr int KSPLIT = 9;              // KT = 256 -> 387 blocks; keeps ws under budget
constexpr int KT     = KF / KSPLIT;
constexpr int NJT    = (AL + JT - 1) / JT;  // 43
constexpr int JTOT   = NJT * JT;            // 2752
constexpr int LPAD   = 68;

// ws layout (bytes): 701,440 + 522,240 + 6,340,608 = 7,564,288 (< prior 9.42 MB)
constexpr size_t ATT_OFF   = 0;                                  // NI*ALP*4
constexpr size_t ARGP_OFF  = (size_t)NI * ALP * 4;
constexpr size_t GEMMP_OFF = ARGP_OFF + (size_t)NI * NKP * NBX * 8;

__device__ __forceinline__ int perm(int j) {
    if (j < OB0)      { int o = j / 34, c = j - o * 34; return TW0 + c * 32 + o; }
    else if (j < OW1) return TB0 + (j - OB0);
    else if (j < OB1) { int q = j - OW1; int o = q >> 5, c = q & 31; return TW1 + c * 32 + o; }
    else if (j < OW2) return TB1 + (j - OB1);
    else if (j < OB2) return TW2 + (j - OW2);
    else              return TB2 + (j - OB2);
}

// ========== kernel 1: attns GEMM partials (no atomics) ==========
__global__ __launch_bounds__(256) void gemm_attn(const float* __restrict__ tf,
                                                 const float* __restrict__ W,
                                                 float* __restrict__ partial) {
    __shared__ __align__(16) float Tl[KCH][LPAD];
    __shared__ __align__(16) float Wl[KCH][LPAD];
    int jb = blockIdx.x % NJT;
    int ks = blockIdx.x / NJT;
    int j0 = jb * JT;
    int k0 = ks * KT;
    int tid = threadIdx.x;
    int tn = tid % 16;
    int tj = tid / 16;
    int lk = tid % 64;
    int lr = tid / 64;
    float acc[4][4] = {};
    for (int kc = 0; kc < KT; kc += KCH) {
        int kbase = k0 + kc;
        #pragma unroll
        for (int i = 0; i < 16; i++) {
            int nn = lr * 16 + i;
            Tl[lk][nn] = tf[(size_t)nn * KF + kbase + lk];
        }
        #pragma unroll
        for (int i = 0; i < 16; i++) {
            int j = j0 + lr * 16 + i;
            Wl[lk][lr * 16 + i] = (j < AL) ? W[(size_t)j * KF + kbase + lk] : 0.0f;
        }
        __syncthreads();
        #pragma unroll 4
        for (int kk = 0; kk < KCH; ++kk) {
            float tv[4], wv[4];
            #pragma unroll
            for (int i = 0; i < 4; i++) tv[i] = Tl[kk][tn * 4 + i];
            #pragma unroll
            for (int i = 0; i < 4; i++) wv[i] = Wl[kk][tj * 4 + i];
            #pragma unroll
            for (int i = 0; i < 4; i++)
                #pragma unroll
                for (int q = 0; q < 4; q++) acc[i][q] += tv[i] * wv[q];
        }
        __syncthreads();
    }
    // plain stores to disjoint per-ks partials (float4, 16B-aligned)
    size_t pbase = (size_t)(ks * NI) * JTOT;
    #pragma unroll
    for (int i = 0; i < 4; i++) {
        int nn = tn * 4 + i;
        int j = j0 + tj * 4;
        float4 st = make_float4(acc[i][0], acc[i][1], acc[i][2], acc[i][3]);
        *(float4*)&partial[pbase + (size_t)nn * JTOT + j] = st;
    }
}

// ========== kernel 2: reduce partials + bias -> permuted att_p ==========
__global__ __launch_bounds__(256) void reduce_attn(const float* __restrict__ partial,
                                                   const float* __restrict__ b,
                                                   float* __restrict__ att_p) {
    int n = blockIdx.y;
    int j = blockIdx.x * 256 + threadIdx.x;
    if (j >= AL) return;
    float s = b[j];
    #pragma unroll
    for (int ks = 0; ks < KSPLIT; ks++)
        s += partial[(size_t)(ks * NI + n) * JTOT + j];
    att_p[(size_t)n * ALP + perm(j)] = s;
}

// ========== kernel 3: fused per-pixel head + block argmax ==========
// All weights are block-uniform (depend only on n = blockIdx.y) -> read them
// through the uniform global pointer so the compiler scalarizes to s_load and
// folds SGPR operands straight into v_fmac. Zero LDS / zero VMEM for weights.
// HARD CONSTRAINT (measured twice): a min-waves launch-bounds arg > 4 makes
// the allocator collapse VGPRs to 32 and spill the h/gg accumulators to
// scratch: (512,8) -> +211 MB scratch, 104->115 us (r3); (256,6) -> +250 MB
// scratch, 98->111 us (r6). Keep the 2nd arg at 4. Runtime occupancy is set
// by ACTUAL usage (VGPR ~48 -> 8 waves/SIMD ok, SGPR ~112 -> 7 waves/SIMD);
// 4-wave (256-thr) blocks pack 1 wave/SIMD so residency can reach that bound,
// unlike 8-wave blocks which quantize at 2 waves/SIMD per block.
__device__ inline unsigned int mono_f32(float f) {
    unsigned int u = __float_as_uint(f);
    return (u & 0x80000000u) ? ~u : (u | 0x80000000u);
}

__global__ __launch_bounds__(256, 4) void pixel_head(const float* __restrict__ bases_full,
                                                     const float* __restrict__ att_p,
                                                     const float* __restrict__ locations,
                                                     const float* __restrict__ soi,
                                                     const int* __restrict__ fpn,
                                                     float* __restrict__ out_logits,
                                                     unsigned long long* __restrict__ partial) {
    __shared__ unsigned long long red[4][NKP];
    int n = blockIdx.y, bx = blockIdx.x, tid = threadIdx.x;
    const float* wn = att_p + (size_t)n * ALP;       // block-uniform base

    int p0 = bx * PXB + tid;
    bool valid = p0 < HW;
    int pc = valid ? p0 : 0;
    int y = pc / WDIM, x = pc - y * WDIM;

    float inv = 1.0f / soi[fpn[n]];
    float lx = locations[2 * n], ly = locations[2 * n + 1];
    float cx = (lx - (float)(x * 8 + 4)) * inv;
    float cy = (ly - (float)(y * 8 + 4)) * inv;

    // issue first bases loads early so latency hides under the offsets FMAs
    const float* bp = bases_full + pc;
    float q0 = bp[0], q1 = bp[HW], q2 = bp[2 * (size_t)HW], q3 = bp[3 * (size_t)HW];

    // ---- layer 0: h = relu(W0 x + b0), c-outer streaming, scalar weights ----
    float h[32];
    {
        const float4* br  = (const float4*)(wn + TB0);
        const float4* w0r = (const float4*)(wn + TW0);
        const float4* w1r = (const float4*)(wn + TW0 + 32);
        #pragma unroll
        for (int g = 0; g < 8; g++) {
            float4 b4 = br[g], wv = w0r[g], wu = w1r[g];
            h[4*g+0] = b4.x + wv.x * cx + wu.x * cy;
            h[4*g+1] = b4.y + wv.y * cx + wu.y * cy;
            h[4*g+2] = b4.z + wv.z * cx + wu.z * cy;
            h[4*g+3] = b4.w + wv.w * cx + wu.w * cy;
        }
    }
    // 4-deep rolling prefetch over the 32 bases channels
    #pragma unroll 2
    for (int c0 = 0; c0 < 32; c0 += 4) {
        float n0 = 0.f, n1 = 0.f, n2 = 0.f, n3 = 0.f;
        if (c0 + 4 < 32) {
            n0 = bp[(size_t)(c0 + 4) * HW];
            n1 = bp[(size_t)(c0 + 5) * HW];
            n2 = bp[(size_t)(c0 + 6) * HW];
            n3 = bp[(size_t)(c0 + 7) * HW];
        }
        float qq[4] = {q0, q1, q2, q3};
        #pragma unroll
        for (int u = 0; u < 4; u++) {
            float bv = qq[u];
            const float4* wr = (const float4*)(wn + TW0 + (c0 + u + 2) * 32);
            #pragma unroll
            for (int g = 0; g < 8; g++) {
                float4 wv = wr[g];
                h[4*g+0] += wv.x * bv;
                h[4*g+1] += wv.y * bv;
                h[4*g+2] += wv.z * bv;
                h[4*g+3] += wv.w * bv;
            }
        }
        q0 = n0; q1 = n1; q2 = n2; q3 = n3;
    }
    #pragma unroll
    for (int o = 0; o < 32; o++) h[o] = fmaxf(h[o], 0.0f);

    // ---- layer 1: scalar weights via uniform global pointer ----
    float gg[32];
    {
        const float4* br = (const float4*)(wn + TB1);
        #pragma unroll
        for (int g = 0; g < 8; g++) {
            float4 b4 = br[g];
            gg[4*g+0] = b4.x; gg[4*g+1] = b4.y; gg[4*g+2] = b4.z; gg[4*g+3] = b4.w;
        }
    }
    #pragma unroll 4
    for (int c = 0; c < 32; c++) {
        float xv = h[c];
        const float4* wr = (const float4*)(wn + TW1 + c * 32);
        #pragma unroll
        for (int g = 0; g < 8; g++) {
            float4 wv = wr[g];
            gg[4*g+0] += wv.x * xv;
            gg[4*g+1] += wv.y * xv;
            gg[4*g+2] += wv.z * xv;
            gg[4*g+3] += wv.w * xv;
        }
    }
    #pragma unroll
    for (int o = 0; o < 32; o++) gg[o] = fmaxf(gg[o], 0.0f);

    // ---- layer 2: scalar weights; store logits + fused per-k argmax ----
    // Wave argmax: 32-bit fp max butterfly, then ballot + ffs for the winning
    // lane (lowest lane = smallest pixel index = numpy first-occurrence).
    size_t obase = (size_t)n * NKP * HW;
    int wid = tid >> 6, lane = tid & 63;
    #pragma unroll
    for (int k = 0; k < NKP; k++) {
        const float4* wr = (const float4*)(wn + TW2 + k * 32);
        float s = wn[TB2 + k];
        #pragma unroll
        for (int g = 0; g < 8; g++) {
            float4 wv = wr[g];
            s += wv.x * gg[4*g+0] + wv.y * gg[4*g+1] + wv.z * gg[4*g+2] + wv.w * gg[4*g+3];
        }
        if (valid)
            __builtin_nontemporal_store(s, &out_logits[obase + (size_t)k * HW + p0]);
        float sm = valid ? s : -__builtin_inff();
        float m = sm;
        #pragma unroll
        for (int off = 32; off > 0; off >>= 1)
            m = fmaxf(m, __shfl_xor(m, off));
        unsigned long long ball = __ballot(sm == m);
        if (lane == 0) {
            int winlane = __ffsll((unsigned long long)ball) - 1;
            unsigned pix = (unsigned)(bx * PXB + (wid << 6) + winlane);
            red[wid][k] = ((unsigned long long)mono_f32(m) << 32) |
                          (unsigned long long)(0xFFFFFFFFu - pix);
        }
    }
    __syncthreads();
    if (tid < NKP) {
        unsigned long long m = red[0][tid];
        #pragma unroll
        for (int ww = 1; ww < 4; ww++)
            if (red[ww][tid] > m) m = red[ww][tid];
        partial[((size_t)n * NKP + tid) * NBX + bx] = m;
    }
}

// ========== kernel 4: final argmax reduce + keypoint ==========
__global__ __launch_bounds__(64) void kp_final(const unsigned long long* __restrict__ partial,
                                               const float* __restrict__ bases_full,
                                               float* __restrict__ kp_out) {
    int b = blockIdx.x;
    int n = b / NKP, k = b % NKP;
    int lane = threadIdx.x;
    unsigned long long v = (lane < NBX) ? partial[((size_t)n * NKP + k) * NBX + lane] : 0ull;
    #pragma unroll
    for (int off = 32; off > 0; off >>= 1) {
        unsigned long long o = __shfl_down(v, off);
        if (o > v) v = o;
    }
    if (lane == 0) {
        int p = (int)(0xFFFFFFFFu - (unsigned)(v & 0xFFFFFFFFull));
        int yy = p / WDIM;
        int xx = p - yy * WDIM;
        float kx = bases_full[(size_t)(NBASES + 2 * k) * HW + p] + (float)(xx * 8 + 4);
        float ky = bases_full[(size_t)(NBASES + 2 * k + 1) * HW + p] + (float)(yy * 8 + 4);
        kp_out[((size_t)n * NKP + k) * 2 + 0] = kx;
        kp_out[((size_t)n * NKP + k) * 2 + 1] = ky;
    }
}

extern "C" void kernel_launch(void* const* d_in, const int* in_sizes, int n_in,
                              void* d_out, int out_size, void* d_ws, size_t ws_size,
                              hipStream_t stream) {
    const float* bases_full = (const float*)d_in[0];
    const float* top_feats  = (const float*)d_in[1];
    const float* locations  = (const float*)d_in[2];
    const float* atten_W    = (const float*)d_in[3];
    const float* atten_b    = (const float*)d_in[4];
    const float* soi        = (const float*)d_in[5];
    const int*   fpn        = (const int*)d_in[6];
    float* out   = (float*)d_out;
    float* att_p = (float*)((char*)d_ws + ATT_OFF);
    unsigned long long* argp = (unsigned long long*)((char*)d_ws + ARGP_OFF);
    float* gemmp = (float*)((char*)d_ws + GEMMP_OFF);

    gemm_attn<<<NJT * KSPLIT, 256, 0, stream>>>(top_feats, atten_W, gemmp);

    dim3 gr((AL + 255) / 256, NI);   // 11 x 64
    reduce_attn<<<gr, 256, 0, stream>>>(gemmp, atten_b, att_p);

    dim3 g2(NBX, NI);   // 60 x 64
    pixel_head<<<g2, 256, 0, stream>>>(bases_full, att_p, locations, soi, fpn, out, argp);

    float* kp_out = out + (size_t)NI * NKP * HW;
    kp_final<<<NI * NKP, 64, 0, stream>>>(argp, bases_full, kp_out);
}

// Round 8
// 214.246 us; speedup vs baseline: 1.0688x; 1.0208x over previous
//
#include <hip/hip_runtime.h>
#include <stdint.h>

// ---- problem constants ----
constexpr int NBASES = 32;
constexpr int NKP    = 17;
constexpr int HDIM   = 100, WDIM = 152;
constexpr int HW     = HDIM * WDIM;       // 15200
constexpr int NI     = 64;
constexpr int KF     = 2304;
constexpr int AL     = 2737;
constexpr int ALP    = 2740;              // padded per-instance stride (16B-aligned rows)
// packed reference offsets inside an attns row
constexpr int OB0 = 1088;
constexpr int OW1 = 1120;
constexpr int OB1 = 2144;
constexpr int OW2 = 2176;
constexpr int OB2 = 2720;
// permuted layout (w0/w1 c-major; w2 k-major)
constexpr int TW0 = 0;      // [34][32]
constexpr int TB0 = 1088;   // 32
constexpr int TW1 = 1120;   // [32][32]
constexpr int TB1 = 2144;   // 32
constexpr int TW2 = 2176;   // [17][32]
constexpr int TB2 = 2720;   // 17

constexpr int PXB = 256;                     // pixels per block (256 thr x 1 px)
constexpr int NBX = (HW + PXB - 1) / PXB;    // 60

// gemm tiling
constexpr int JT     = 64;
constexpr int KCH    = 64;
constexpr int KSPLIT = 9;              // KT = 256 -> 387 blocks; keeps ws under budget
constexpr int KT     = KF / KSPLIT;
constexpr int NJT    = (AL + JT - 1) / JT;  // 43
constexpr int JTOT   = NJT * JT;            // 2752
constexpr int LPAD   = 68;

// ws layout (bytes): 701,440 + 522,240 + 6,340,608 = 7,564,288
constexpr size_t ATT_OFF   = 0;                                  // NI*ALP*4
constexpr size_t ARGP_OFF  = (size_t)NI * ALP * 4;
constexpr size_t GEMMP_OFF = ARGP_OFF + (size_t)NI * NKP * NBX * 8;

__device__ __forceinline__ int perm(int j) {
    if (j < OB0)      { int o = j / 34, c = j - o * 34; return TW0 + c * 32 + o; }
    else if (j < OW1) return TB0 + (j - OB0);
    else if (j < OB1) { int q = j - OW1; int o = q >> 5, c = q & 31; return TW1 + c * 32 + o; }
    else if (j < OW2) return TB1 + (j - OB1);
    else if (j < OB2) return TW2 + (j - OW2);
    else              return TB2 + (j - OB2);
}

// ========== kernel 1: attns GEMM partials (no atomics) ==========
__global__ __launch_bounds__(256) void gemm_attn(const float* __restrict__ tf,
                                                 const float* __restrict__ W,
                                                 float* __restrict__ partial) {
    __shared__ __align__(16) float Tl[KCH][LPAD];
    __shared__ __align__(16) float Wl[KCH][LPAD];
    int jb = blockIdx.x % NJT;
    int ks = blockIdx.x / NJT;
    int j0 = jb * JT;
    int k0 = ks * KT;
    int tid = threadIdx.x;
    int tn = tid % 16;
    int tj = tid / 16;
    int lk = tid % 64;
    int lr = tid / 64;
    float acc[4][4] = {};
    for (int kc = 0; kc < KT; kc += KCH) {
        int kbase = k0 + kc;
        #pragma unroll
        for (int i = 0; i < 16; i++) {
            int nn = lr * 16 + i;
            Tl[lk][nn] = tf[(size_t)nn * KF + kbase + lk];
        }
        #pragma unroll
        for (int i = 0; i < 16; i++) {
            int j = j0 + lr * 16 + i;
            Wl[lk][lr * 16 + i] = (j < AL) ? W[(size_t)j * KF + kbase + lk] : 0.0f;
        }
        __syncthreads();
        #pragma unroll 4
        for (int kk = 0; kk < KCH; ++kk) {
            float tv[4], wv[4];
            #pragma unroll
            for (int i = 0; i < 4; i++) tv[i] = Tl[kk][tn * 4 + i];
            #pragma unroll
            for (int i = 0; i < 4; i++) wv[i] = Wl[kk][tj * 4 + i];
            #pragma unroll
            for (int i = 0; i < 4; i++)
                #pragma unroll
                for (int q = 0; q < 4; q++) acc[i][q] += tv[i] * wv[q];
        }
        __syncthreads();
    }
    // plain stores to disjoint per-ks partials (float4, 16B-aligned)
    size_t pbase = (size_t)(ks * NI) * JTOT;
    #pragma unroll
    for (int i = 0; i < 4; i++) {
        int nn = tn * 4 + i;
        int j = j0 + tj * 4;
        float4 st = make_float4(acc[i][0], acc[i][1], acc[i][2], acc[i][3]);
        *(float4*)&partial[pbase + (size_t)nn * JTOT + j] = st;
    }
}

// ========== kernel 2: reduce partials + bias -> permuted att_p ==========
__global__ __launch_bounds__(256) void reduce_attn(const float* __restrict__ partial,
                                                   const float* __restrict__ b,
                                                   float* __restrict__ att_p) {
    int n = blockIdx.y;
    int j = blockIdx.x * 256 + threadIdx.x;
    if (j >= AL) return;
    float s = b[j];
    #pragma unroll
    for (int ks = 0; ks < KSPLIT; ks++)
        s += partial[(size_t)(ks * NI + n) * JTOT + j];
    att_p[(size_t)n * ALP + perm(j)] = s;
}

// ========== kernel 3: fused per-pixel head + block argmax ==========
// All weights are block-uniform (depend only on n = blockIdx.y) -> read them
// through the uniform global pointer so the compiler scalarizes to s_load and
// folds SGPR operands straight into v_fmac. Zero LDS / zero VMEM for weights.
// HARD CONSTRAINT (measured twice): a min-waves launch-bounds arg > 4 makes
// the allocator collapse VGPRs to 32 and spill the h/gg accumulators to
// scratch: (512,8) -> +211 MB scratch, 104->115 us (r3); (256,6) -> +250 MB
// scratch, 98->111 us (r6). Keep the 2nd arg at 4.
// ARGMAX (r8): two-stage LDS argmax replaces the per-k shuffle butterfly.
// The 6-step ds_swizzle chain per k (x17, serially dependent, ~100cyc/step,
// hit by all waves in lockstep) was the dominant unhidden-latency region.
// Stage 1: one conflict-free ds_write per k, overlapped with the FMA stream.
// Stage 2: 255 threads scan 17 strands of ~17 values (ascending index,
// strict >, preserving numpy first-occurrence), then 17 threads reduce.
__device__ inline unsigned int mono_f32(float f) {
    unsigned int u = __float_as_uint(f);
    return (u & 0x80000000u) ? ~u : (u | 0x80000000u);
}

__global__ __launch_bounds__(256, 4) void pixel_head(const float* __restrict__ bases_full,
                                                     const float* __restrict__ att_p,
                                                     const float* __restrict__ locations,
                                                     const float* __restrict__ soi,
                                                     const int* __restrict__ fpn,
                                                     float* __restrict__ out_logits,
                                                     unsigned long long* __restrict__ partial) {
    __shared__ float smax[NKP][257];                 // stride 257: de-conflicts stage-2 reads
    __shared__ unsigned long long cand[NKP][16];
    int n = blockIdx.y, bx = blockIdx.x, tid = threadIdx.x;
    const float* wn = att_p + (size_t)n * ALP;       // block-uniform base

    int p0 = bx * PXB + tid;
    bool valid = p0 < HW;
    int pc = valid ? p0 : 0;
    int y = pc / WDIM, x = pc - y * WDIM;

    float inv = 1.0f / soi[fpn[n]];
    float lx = locations[2 * n], ly = locations[2 * n + 1];
    float cx = (lx - (float)(x * 8 + 4)) * inv;
    float cy = (ly - (float)(y * 8 + 4)) * inv;

    // issue first bases loads early so latency hides under the offsets FMAs
    const float* bp = bases_full + pc;
    float q0 = bp[0], q1 = bp[HW], q2 = bp[2 * (size_t)HW], q3 = bp[3 * (size_t)HW];

    // ---- layer 0: h = relu(W0 x + b0), c-outer streaming, scalar weights ----
    float h[32];
    {
        const float4* br  = (const float4*)(wn + TB0);
        const float4* w0r = (const float4*)(wn + TW0);
        const float4* w1r = (const float4*)(wn + TW0 + 32);
        #pragma unroll
        for (int g = 0; g < 8; g++) {
            float4 b4 = br[g], wv = w0r[g], wu = w1r[g];
            h[4*g+0] = b4.x + wv.x * cx + wu.x * cy;
            h[4*g+1] = b4.y + wv.y * cx + wu.y * cy;
            h[4*g+2] = b4.z + wv.z * cx + wu.z * cy;
            h[4*g+3] = b4.w + wv.w * cx + wu.w * cy;
        }
    }
    // 4-deep rolling prefetch over the 32 bases channels
    #pragma unroll 2
    for (int c0 = 0; c0 < 32; c0 += 4) {
        float n0 = 0.f, n1 = 0.f, n2 = 0.f, n3 = 0.f;
        if (c0 + 4 < 32) {
            n0 = bp[(size_t)(c0 + 4) * HW];
            n1 = bp[(size_t)(c0 + 5) * HW];
            n2 = bp[(size_t)(c0 + 6) * HW];
            n3 = bp[(size_t)(c0 + 7) * HW];
        }
        float qq[4] = {q0, q1, q2, q3};
        #pragma unroll
        for (int u = 0; u < 4; u++) {
            float bv = qq[u];
            const float4* wr = (const float4*)(wn + TW0 + (c0 + u + 2) * 32);
            #pragma unroll
            for (int g = 0; g < 8; g++) {
                float4 wv = wr[g];
                h[4*g+0] += wv.x * bv;
                h[4*g+1] += wv.y * bv;
                h[4*g+2] += wv.z * bv;
                h[4*g+3] += wv.w * bv;
            }
        }
        q0 = n0; q1 = n1; q2 = n2; q3 = n3;
    }
    #pragma unroll
    for (int o = 0; o < 32; o++) h[o] = fmaxf(h[o], 0.0f);

    // ---- layer 1: scalar weights via uniform global pointer ----
    float gg[32];
    {
        const float4* br = (const float4*)(wn + TB1);
        #pragma unroll
        for (int g = 0; g < 8; g++) {
            float4 b4 = br[g];
            gg[4*g+0] = b4.x; gg[4*g+1] = b4.y; gg[4*g+2] = b4.z; gg[4*g+3] = b4.w;
        }
    }
    #pragma unroll 4
    for (int c = 0; c < 32; c++) {
        float xv = h[c];
        const float4* wr = (const float4*)(wn + TW1 + c * 32);
        #pragma unroll
        for (int g = 0; g < 8; g++) {
            float4 wv = wr[g];
            gg[4*g+0] += wv.x * xv;
            gg[4*g+1] += wv.y * xv;
            gg[4*g+2] += wv.z * xv;
            gg[4*g+3] += wv.w * xv;
        }
    }
    #pragma unroll
    for (int o = 0; o < 32; o++) gg[o] = fmaxf(gg[o], 0.0f);

    // ---- layer 2: scalar weights; store logits + LDS stage-1 write ----
    size_t obase = (size_t)n * NKP * HW;
    #pragma unroll
    for (int k = 0; k < NKP; k++) {
        const float4* wr = (const float4*)(wn + TW2 + k * 32);
        float s = wn[TB2 + k];
        #pragma unroll
        for (int g = 0; g < 8; g++) {
            float4 wv = wr[g];
            s += wv.x * gg[4*g+0] + wv.y * gg[4*g+1] + wv.z * gg[4*g+2] + wv.w * gg[4*g+3];
        }
        if (valid)
            __builtin_nontemporal_store(s, &out_logits[obase + (size_t)k * HW + p0]);
        smax[k][tid] = valid ? s : -__builtin_inff();
    }
    __syncthreads();

    // ---- stage 2a: 17 k's x 15 strands, ascending-index strict-> scan ----
    if (tid < 255) {
        int k = tid / 15, j = tid % 15;
        float bv = -__builtin_inff();
        int bi = 0;
        for (int i = j; i < 256; i += 15) {
            float v = smax[k][i];
            if (v > bv) { bv = v; bi = i; }
        }
        unsigned pix = (unsigned)(bx * PXB + bi);
        cand[k][j] = ((unsigned long long)mono_f32(bv) << 32) |
                     (unsigned long long)(0xFFFFFFFFu - pix);
    }
    __syncthreads();

    // ---- stage 2b: 17 threads reduce 15 candidates each ----
    if (tid < NKP) {
        unsigned long long m = cand[tid][0];
        #pragma unroll
        for (int j = 1; j < 15; j++)
            if (cand[tid][j] > m) m = cand[tid][j];
        partial[((size_t)n * NKP + tid) * NBX + bx] = m;
    }
}

// ========== kernel 4: final argmax reduce + keypoint ==========
__global__ __launch_bounds__(64) void kp_final(const unsigned long long* __restrict__ partial,
                                               const float* __restrict__ bases_full,
                                               float* __restrict__ kp_out) {
    int b = blockIdx.x;
    int n = b / NKP, k = b % NKP;
    int lane = threadIdx.x;
    unsigned long long v = (lane < NBX) ? partial[((size_t)n * NKP + k) * NBX + lane] : 0ull;
    #pragma unroll
    for (int off = 32; off > 0; off >>= 1) {
        unsigned long long o = __shfl_down(v, off);
        if (o > v) v = o;
    }
    if (lane == 0) {
        int p = (int)(0xFFFFFFFFu - (unsigned)(v & 0xFFFFFFFFull));
        int yy = p / WDIM;
        int xx = p - yy * WDIM;
        float kx = bases_full[(size_t)(NBASES + 2 * k) * HW + p] + (float)(xx * 8 + 4);
        float ky = bases_full[(size_t)(NBASES + 2 * k + 1) * HW + p] + (float)(yy * 8 + 4);
        kp_out[((size_t)n * NKP + k) * 2 + 0] = kx;
        kp_out[((size_t)n * NKP + k) * 2 + 1] = ky;
    }
}

extern "C" void kernel_launch(void* const* d_in, const int* in_sizes, int n_in,
                              void* d_out, int out_size, void* d_ws, size_t ws_size,
                              hipStream_t stream) {
    const float* bases_full = (const float*)d_in[0];
    const float* top_feats  = (const float*)d_in[1];
    const float* locations  = (const float*)d_in[2];
    const float* atten_W    = (const float*)d_in[3];
    const float* atten_b    = (const float*)d_in[4];
    const float* soi        = (const float*)d_in[5];
    const int*   fpn        = (const int*)d_in[6];
    float* out   = (float*)d_out;
    float* att_p = (float*)((char*)d_ws + ATT_OFF);
    unsigned long long* argp = (unsigned long long*)((char*)d_ws + ARGP_OFF);
    float* gemmp = (float*)((char*)d_ws + GEMMP_OFF);

    gemm_attn<<<NJT * KSPLIT, 256, 0, stream>>>(top_feats, atten_W, gemmp);

    dim3 gr((AL + 255) / 256, NI);   // 11 x 64
    reduce_attn<<<gr, 256, 0, stream>>>(gemmp, atten_b, att_p);

    dim3 g2(NBX, NI);   // 60 x 64
    pixel_head<<<g2, 256, 0, stream>>>(bases_full, att_p, locations, soi, fpn, out, argp);

    float* kp_out = out + (size_t)NI * NKP * HW;
    kp_final<<<NI * NKP, 64, 0, stream>>>(argp, bases_full, kp_out);
}

// Round 9
// 212.412 us; speedup vs baseline: 1.0781x; 1.0086x over previous
//
#include <hip/hip_runtime.h>
#include <stdint.h>

// ---- problem constants ----
constexpr int NBASES = 32;
constexpr int NKP    = 17;
constexpr int HDIM   = 100, WDIM = 152;
constexpr int HW     = HDIM * WDIM;       // 15200
constexpr int NI     = 64;
constexpr int KF     = 2304;
constexpr int AL     = 2737;
constexpr int ALP    = 2740;              // padded per-instance stride (16B-aligned rows)
// packed reference offsets inside an attns row
constexpr int OB0 = 1088;
constexpr int OW1 = 1120;
constexpr int OB1 = 2144;
constexpr int OW2 = 2176;
constexpr int OB2 = 2720;
// permuted layout (w0/w1 c-major; w2 k-major)
constexpr int TW0 = 0;      // [34][32]
constexpr int TB0 = 1088;   // 32
constexpr int TW1 = 1120;   // [32][32]
constexpr int TB1 = 2144;   // 32
constexpr int TW2 = 2176;   // [17][32]
constexpr int TB2 = 2720;   // 17

constexpr int PXB = 256;                     // pixels per block (256 thr x 1 px)
constexpr int NBX = (HW + PXB - 1) / PXB;    // 60

// gemm tiling
constexpr int JT     = 64;
constexpr int KCH    = 64;
constexpr int KSPLIT = 9;              // KT = 256 -> 387 blocks; keeps ws under budget
constexpr int KT     = KF / KSPLIT;
constexpr int NJT    = (AL + JT - 1) / JT;  // 43
constexpr int JTOT   = NJT * JT;            // 2752
constexpr int LPAD   = 68;

// ws layout (bytes): 701,440 + 522,240 + 6,340,608 = 7,564,288
constexpr size_t ATT_OFF   = 0;                                  // NI*ALP*4
constexpr size_t ARGP_OFF  = (size_t)NI * ALP * 4;
constexpr size_t GEMMP_OFF = ARGP_OFF + (size_t)NI * NKP * NBX * 8;

typedef float v2f __attribute__((ext_vector_type(2)));

__device__ __forceinline__ int perm(int j) {
    if (j < OB0)      { int o = j / 34, c = j - o * 34; return TW0 + c * 32 + o; }
    else if (j < OW1) return TB0 + (j - OB0);
    else if (j < OB1) { int q = j - OW1; int o = q >> 5, c = q & 31; return TW1 + c * 32 + o; }
    else if (j < OW2) return TB1 + (j - OB1);
    else if (j < OB2) return TW2 + (j - OW2);
    else              return TB2 + (j - OB2);
}

// ========== kernel 1: attns GEMM partials (no atomics) ==========
__global__ __launch_bounds__(256) void gemm_attn(const float* __restrict__ tf,
                                                 const float* __restrict__ W,
                                                 float* __restrict__ partial) {
    __shared__ __align__(16) float Tl[KCH][LPAD];
    __shared__ __align__(16) float Wl[KCH][LPAD];
    int jb = blockIdx.x % NJT;
    int ks = blockIdx.x / NJT;
    int j0 = jb * JT;
    int k0 = ks * KT;
    int tid = threadIdx.x;
    int tn = tid % 16;
    int tj = tid / 16;
    int lk = tid % 64;
    int lr = tid / 64;
    float acc[4][4] = {};
    for (int kc = 0; kc < KT; kc += KCH) {
        int kbase = k0 + kc;
        #pragma unroll
        for (int i = 0; i < 16; i++) {
            int nn = lr * 16 + i;
            Tl[lk][nn] = tf[(size_t)nn * KF + kbase + lk];
        }
        #pragma unroll
        for (int i = 0; i < 16; i++) {
            int j = j0 + lr * 16 + i;
            Wl[lk][lr * 16 + i] = (j < AL) ? W[(size_t)j * KF + kbase + lk] : 0.0f;
        }
        __syncthreads();
        #pragma unroll 4
        for (int kk = 0; kk < KCH; ++kk) {
            float tv[4], wv[4];
            #pragma unroll
            for (int i = 0; i < 4; i++) tv[i] = Tl[kk][tn * 4 + i];
            #pragma unroll
            for (int i = 0; i < 4; i++) wv[i] = Wl[kk][tj * 4 + i];
            #pragma unroll
            for (int i = 0; i < 4; i++)
                #pragma unroll
                for (int q = 0; q < 4; q++) acc[i][q] += tv[i] * wv[q];
        }
        __syncthreads();
    }
    // plain stores to disjoint per-ks partials (float4, 16B-aligned)
    size_t pbase = (size_t)(ks * NI) * JTOT;
    #pragma unroll
    for (int i = 0; i < 4; i++) {
        int nn = tn * 4 + i;
        int j = j0 + tj * 4;
        float4 st = make_float4(acc[i][0], acc[i][1], acc[i][2], acc[i][3]);
        *(float4*)&partial[pbase + (size_t)nn * JTOT + j] = st;
    }
}

// ========== kernel 2: reduce partials + bias -> permuted att_p ==========
__global__ __launch_bounds__(256) void reduce_attn(const float* __restrict__ partial,
                                                   const float* __restrict__ b,
                                                   float* __restrict__ att_p) {
    int n = blockIdx.y;
    int j = blockIdx.x * 256 + threadIdx.x;
    if (j >= AL) return;
    float s = b[j];
    #pragma unroll
    for (int ks = 0; ks < KSPLIT; ks++)
        s += partial[(size_t)(ks * NI + n) * JTOT + j];
    att_p[(size_t)n * ALP + perm(j)] = s;
}

// ========== kernel 3: fused per-pixel head + block argmax ==========
// All weights are block-uniform (depend only on n = blockIdx.y) -> read them
// through the uniform global pointer so the compiler scalarizes to s_load and
// folds SGPR operands straight into the FMA. Zero VMEM for weights.
// PACKED MATH (r9): layer loops operate on float2 (ext_vector_type) pairs so
// ISel can emit v_pk_fma_f32 (VOP3P, 2 FMA/inst) -- the kernel is VALU-issue
// bound (busy 67us vs ~50us scalar-FMA floor), so halving inst count is the
// remaining lever. Weight reads stay uniform (s_load_dwordx2 pairs).
// HARD CONSTRAINT (measured twice): a min-waves launch-bounds arg > 4 makes
// the allocator collapse VGPRs to 32 and spill the h/gg accumulators to
// scratch: (512,8) r3, (256,6) r6 -> +200+ MB scratch traffic. Keep arg = 4.
// ARGMAX (r8, kept): two-stage LDS argmax; the per-k ds_swizzle butterfly was
// serial unhidden latency (100.4 -> 95.6 us).
__device__ inline unsigned int mono_f32(float f) {
    unsigned int u = __float_as_uint(f);
    return (u & 0x80000000u) ? ~u : (u | 0x80000000u);
}

__global__ __launch_bounds__(256, 4) void pixel_head(const float* __restrict__ bases_full,
                                                     const float* __restrict__ att_p,
                                                     const float* __restrict__ locations,
                                                     const float* __restrict__ soi,
                                                     const int* __restrict__ fpn,
                                                     float* __restrict__ out_logits,
                                                     unsigned long long* __restrict__ partial) {
    __shared__ float smax[NKP][257];                 // stride 257: de-conflicts stage-2 reads
    __shared__ unsigned long long cand[NKP][16];
    int n = blockIdx.y, bx = blockIdx.x, tid = threadIdx.x;
    const float* wn = att_p + (size_t)n * ALP;       // block-uniform base

    int p0 = bx * PXB + tid;
    bool valid = p0 < HW;
    int pc = valid ? p0 : 0;
    int y = pc / WDIM, x = pc - y * WDIM;

    float inv = 1.0f / soi[fpn[n]];
    float lx = locations[2 * n], ly = locations[2 * n + 1];
    float cx = (lx - (float)(x * 8 + 4)) * inv;
    float cy = (ly - (float)(y * 8 + 4)) * inv;

    // issue first bases loads early so latency hides under the offsets FMAs
    const float* bp = bases_full + pc;
    float q0 = bp[0], q1 = bp[HW], q2 = bp[2 * (size_t)HW], q3 = bp[3 * (size_t)HW];

    // ---- layer 0: h = relu(W0 x + b0), c-outer streaming, packed pairs ----
    v2f h2[16];
    {
        const v2f* br  = (const v2f*)(wn + TB0);
        const v2f* w0r = (const v2f*)(wn + TW0);
        const v2f* w1r = (const v2f*)(wn + TW0 + 32);
        v2f cx2 = cx, cy2 = cy;
        #pragma unroll
        for (int g = 0; g < 16; g++)
            h2[g] = br[g] + w0r[g] * cx2 + w1r[g] * cy2;
    }
    // 4-deep rolling prefetch over the 32 bases channels
    #pragma unroll 2
    for (int c0 = 0; c0 < 32; c0 += 4) {
        float n0 = 0.f, n1 = 0.f, n2 = 0.f, n3 = 0.f;
        if (c0 + 4 < 32) {
            n0 = bp[(size_t)(c0 + 4) * HW];
            n1 = bp[(size_t)(c0 + 5) * HW];
            n2 = bp[(size_t)(c0 + 6) * HW];
            n3 = bp[(size_t)(c0 + 7) * HW];
        }
        float qq[4] = {q0, q1, q2, q3};
        #pragma unroll
        for (int u = 0; u < 4; u++) {
            v2f bv2 = qq[u];
            const v2f* wr = (const v2f*)(wn + TW0 + (c0 + u + 2) * 32);
            #pragma unroll
            for (int g = 0; g < 16; g++)
                h2[g] += wr[g] * bv2;
        }
        q0 = n0; q1 = n1; q2 = n2; q3 = n3;
    }
    #pragma unroll
    for (int g = 0; g < 16; g++) {
        h2[g].x = fmaxf(h2[g].x, 0.0f);
        h2[g].y = fmaxf(h2[g].y, 0.0f);
    }

    // ---- layer 1: packed pairs, scalar-broadcast activations ----
    v2f g2[16];
    {
        const v2f* br = (const v2f*)(wn + TB1);
        #pragma unroll
        for (int g = 0; g < 16; g++) g2[g] = br[g];
    }
    #pragma unroll 4
    for (int c = 0; c < 32; c++) {
        v2f xv2 = (c & 1) ? h2[c >> 1].y : h2[c >> 1].x;
        const v2f* wr = (const v2f*)(wn + TW1 + c * 32);
        #pragma unroll
        for (int g = 0; g < 16; g++)
            g2[g] += wr[g] * xv2;
    }
    #pragma unroll
    for (int g = 0; g < 16; g++) {
        g2[g].x = fmaxf(g2[g].x, 0.0f);
        g2[g].y = fmaxf(g2[g].y, 0.0f);
    }

    // ---- layer 2: packed dot products; store logits + LDS stage-1 write ----
    size_t obase = (size_t)n * NKP * HW;
    #pragma unroll
    for (int k = 0; k < NKP; k++) {
        const v2f* wr = (const v2f*)(wn + TW2 + k * 32);
        v2f s2 = wr[0] * g2[0];
        #pragma unroll
        for (int g = 1; g < 16; g++)
            s2 += wr[g] * g2[g];
        float s = wn[TB2 + k] + s2.x + s2.y;
        if (valid)
            __builtin_nontemporal_store(s, &out_logits[obase + (size_t)k * HW + p0]);
        smax[k][tid] = valid ? s : -__builtin_inff();
    }
    __syncthreads();

    // ---- stage 2a: 17 k's x 15 strands, ascending-index strict-> scan ----
    if (tid < 255) {
        int k = tid / 15, j = tid % 15;
        float bv = -__builtin_inff();
        int bi = 0;
        for (int i = j; i < 256; i += 15) {
            float v = smax[k][i];
            if (v > bv) { bv = v; bi = i; }
        }
        unsigned pix = (unsigned)(bx * PXB + bi);
        cand[k][j] = ((unsigned long long)mono_f32(bv) << 32) |
                     (unsigned long long)(0xFFFFFFFFu - pix);
    }
    __syncthreads();

    // ---- stage 2b: 17 threads reduce 15 candidates each ----
    if (tid < NKP) {
        unsigned long long m = cand[tid][0];
        #pragma unroll
        for (int j = 1; j < 15; j++)
            if (cand[tid][j] > m) m = cand[tid][j];
        partial[((size_t)n * NKP + tid) * NBX + bx] = m;
    }
}

// ========== kernel 4: final argmax reduce + keypoint ==========
__global__ __launch_bounds__(64) void kp_final(const unsigned long long* __restrict__ partial,
                                               const float* __restrict__ bases_full,
                                               float* __restrict__ kp_out) {
    int b = blockIdx.x;
    int n = b / NKP, k = b % NKP;
    int lane = threadIdx.x;
    unsigned long long v = (lane < NBX) ? partial[((size_t)n * NKP + k) * NBX + lane] : 0ull;
    #pragma unroll
    for (int off = 32; off > 0; off >>= 1) {
        unsigned long long o = __shfl_down(v, off);
        if (o > v) v = o;
    }
    if (lane == 0) {
        int p = (int)(0xFFFFFFFFu - (unsigned)(v & 0xFFFFFFFFull));
        int yy = p / WDIM;
        int xx = p - yy * WDIM;
        float kx = bases_full[(size_t)(NBASES + 2 * k) * HW + p] + (float)(xx * 8 + 4);
        float ky = bases_full[(size_t)(NBASES + 2 * k + 1) * HW + p] + (float)(yy * 8 + 4);
        kp_out[((size_t)n * NKP + k) * 2 + 0] = kx;
        kp_out[((size_t)n * NKP + k) * 2 + 1] = ky;
    }
}

extern "C" void kernel_launch(void* const* d_in, const int* in_sizes, int n_in,
                              void* d_out, int out_size, void* d_ws, size_t ws_size,
                              hipStream_t stream) {
    const float* bases_full = (const float*)d_in[0];
    const float* top_feats  = (const float*)d_in[1];
    const float* locations  = (const float*)d_in[2];
    const float* atten_W    = (const float*)d_in[3];
    const float* atten_b    = (const float*)d_in[4];
    const float* soi        = (const float*)d_in[5];
    const int*   fpn        = (const int*)d_in[6];
    float* out   = (float*)d_out;
    float* att_p = (float*)((char*)d_ws + ATT_OFF);
    unsigned long long* argp = (unsigned long long*)((char*)d_ws + ARGP_OFF);
    float* gemmp = (float*)((char*)d_ws + GEMMP_OFF);

    gemm_attn<<<NJT * KSPLIT, 256, 0, stream>>>(top_feats, atten_W, gemmp);

    dim3 gr((AL + 255) / 256, NI);   // 11 x 64
    reduce_attn<<<gr, 256, 0, stream>>>(gemmp, atten_b, att_p);

    dim3 g2(NBX, NI);   // 60 x 64
    pixel_head<<<g2, 256, 0, stream>>>(bases_full, att_p, locations, soi, fpn, out, argp);

    float* kp_out = out + (size_t)NI * NKP * HW;
    kp_final<<<NI * NKP, 64, 0, stream>>>(argp, bases_full, kp_out);
}

// Round 10
// 204.901 us; speedup vs baseline: 1.1176x; 1.0367x over previous
//
#include <hip/hip_runtime.h>
#include <stdint.h>

// ---- problem constants ----
constexpr int NBASES = 32;
constexpr int NKP    = 17;
constexpr int HDIM   = 100, WDIM = 152;
constexpr int HW     = HDIM * WDIM;       // 15200
constexpr int NI     = 64;
constexpr int KF     = 2304;
constexpr int AL     = 2737;
constexpr int ALP    = 2740;              // padded per-instance stride (16B-aligned rows)
// packed reference offsets inside an attns row
constexpr int OB0 = 1088;
constexpr int OW1 = 1120;
constexpr int OB1 = 2144;
constexpr int OW2 = 2176;
constexpr int OB2 = 2720;
// permuted layout (w0/w1 c-major; w2 k-major)
constexpr int TW0 = 0;      // [34][32]
constexpr int TB0 = 1088;   // 32
constexpr int TW1 = 1120;   // [32][32]
constexpr int TB1 = 2144;   // 32
constexpr int TW2 = 2176;   // [17][32]
constexpr int TB2 = 2720;   // 17

constexpr int PXB = 512;                     // pixels per block (512 thr x 1 px)
constexpr int NBX = (HW + PXB - 1) / PXB;    // 30

// gemm tiling
// KSPLIT=12 (KT=192, 516 blocks ~ 2.0/CU balanced x 3 K-iters) measured 6-8us
// better RESIDUAL than KSPLIT=9 (387 blocks ~ 1.5/CU imbalanced x 4 K-iters):
// residuals r0/r2/r4 (KS12) = 110-115us vs r6-r9 (KS9) = 118-121us.
constexpr int JT     = 64;
constexpr int KCH    = 64;
constexpr int KSPLIT = 12;
constexpr int KT     = KF / KSPLIT;          // 192
constexpr int NJT    = (AL + JT - 1) / JT;   // 43
constexpr int JTOT   = NJT * JT;             // 2752
constexpr int LPAD   = 68;

// ws layout (bytes): 701,440 + 261,120 + 8,454,144 = 9,416,704 (r4-proven)
constexpr size_t ATT_OFF   = 0;                                  // NI*ALP*4
constexpr size_t ARGP_OFF  = (size_t)NI * ALP * 4;
constexpr size_t GEMMP_OFF = ARGP_OFF + (size_t)NI * NKP * NBX * 8;

typedef float v2f __attribute__((ext_vector_type(2)));

__device__ __forceinline__ int perm(int j) {
    if (j < OB0)      { int o = j / 34, c = j - o * 34; return TW0 + c * 32 + o; }
    else if (j < OW1) return TB0 + (j - OB0);
    else if (j < OB1) { int q = j - OW1; int o = q >> 5, c = q & 31; return TW1 + c * 32 + o; }
    else if (j < OW2) return TB1 + (j - OB1);
    else if (j < OB2) return TW2 + (j - OW2);
    else              return TB2 + (j - OB2);
}

// ========== kernel 1: attns GEMM partials (no atomics) ==========
__global__ __launch_bounds__(256) void gemm_attn(const float* __restrict__ tf,
                                                 const float* __restrict__ W,
                                                 float* __restrict__ partial) {
    __shared__ __align__(16) float Tl[KCH][LPAD];
    __shared__ __align__(16) float Wl[KCH][LPAD];
    int jb = blockIdx.x % NJT;
    int ks = blockIdx.x / NJT;
    int j0 = jb * JT;
    int k0 = ks * KT;
    int tid = threadIdx.x;
    int tn = tid % 16;
    int tj = tid / 16;
    int lk = tid % 64;
    int lr = tid / 64;
    float acc[4][4] = {};
    for (int kc = 0; kc < KT; kc += KCH) {
        int kbase = k0 + kc;
        #pragma unroll
        for (int i = 0; i < 16; i++) {
            int nn = lr * 16 + i;
            Tl[lk][nn] = tf[(size_t)nn * KF + kbase + lk];
        }
        #pragma unroll
        for (int i = 0; i < 16; i++) {
            int j = j0 + lr * 16 + i;
            Wl[lk][lr * 16 + i] = (j < AL) ? W[(size_t)j * KF + kbase + lk] : 0.0f;
        }
        __syncthreads();
        #pragma unroll 4
        for (int kk = 0; kk < KCH; ++kk) {
            float tv[4], wv[4];
            #pragma unroll
            for (int i = 0; i < 4; i++) tv[i] = Tl[kk][tn * 4 + i];
            #pragma unroll
            for (int i = 0; i < 4; i++) wv[i] = Wl[kk][tj * 4 + i];
            #pragma unroll
            for (int i = 0; i < 4; i++)
                #pragma unroll
                for (int q = 0; q < 4; q++) acc[i][q] += tv[i] * wv[q];
        }
        __syncthreads();
    }
    // plain stores to disjoint per-ks partials (float4, 16B-aligned)
    size_t pbase = (size_t)(ks * NI) * JTOT;
    #pragma unroll
    for (int i = 0; i < 4; i++) {
        int nn = tn * 4 + i;
        int j = j0 + tj * 4;
        float4 st = make_float4(acc[i][0], acc[i][1], acc[i][2], acc[i][3]);
        *(float4*)&partial[pbase + (size_t)nn * JTOT + j] = st;
    }
}

// ========== kernel 2: reduce partials + bias -> permuted att_p ==========
__global__ __launch_bounds__(256) void reduce_attn(const float* __restrict__ partial,
                                                   const float* __restrict__ b,
                                                   float* __restrict__ att_p) {
    int n = blockIdx.y;
    int j = blockIdx.x * 256 + threadIdx.x;
    if (j >= AL) return;
    float s = b[j];
    #pragma unroll
    for (int ks = 0; ks < KSPLIT; ks++)
        s += partial[(size_t)(ks * NI + n) * JTOT + j];
    att_p[(size_t)n * ALP + perm(j)] = s;
}

// ========== kernel 3: fused per-pixel head + block argmax ==========
// All weights are block-uniform (depend only on n = blockIdx.y) -> read them
// through the uniform global pointer so the compiler scalarizes to s_load and
// folds SGPR operands straight into the FMA. Zero VMEM for weights.
// PACKED MATH (r9, kept): float2 ext_vector ops let ISel emit v_pk_fma_f32
// for part of the stream (95.6 -> 91.5 us; partial emission, VGPR unchanged).
// HARD CONSTRAINT (measured twice): a min-waves launch-bounds arg > 4 makes
// the allocator collapse VGPRs to 32 and spill the h/gg accumulators to
// scratch: (512,8) r3, (256,6) r6 -> +200+ MB scratch traffic. Keep arg = 4.
// ARGMAX (r8, kept): two-stage LDS argmax; the per-k ds_swizzle butterfly was
// serial unhidden latency (100.4 -> 95.6 us).
__device__ inline unsigned int mono_f32(float f) {
    unsigned int u = __float_as_uint(f);
    return (u & 0x80000000u) ? ~u : (u | 0x80000000u);
}

__global__ __launch_bounds__(512, 4) void pixel_head(const float* __restrict__ bases_full,
                                                     const float* __restrict__ att_p,
                                                     const float* __restrict__ locations,
                                                     const float* __restrict__ soi,
                                                     const int* __restrict__ fpn,
                                                     float* __restrict__ out_logits,
                                                     unsigned long long* __restrict__ partial) {
    __shared__ float smax[NKP][520];                 // stride 520: de-conflicts stage-2 reads
    __shared__ unsigned long long cand[NKP][32];
    int n = blockIdx.y, bx = blockIdx.x, tid = threadIdx.x;
    const float* wn = att_p + (size_t)n * ALP;       // block-uniform base

    int p0 = bx * PXB + tid;
    bool valid = p0 < HW;
    int pc = valid ? p0 : 0;
    int y = pc / WDIM, x = pc - y * WDIM;

    float inv = 1.0f / soi[fpn[n]];
    float lx = locations[2 * n], ly = locations[2 * n + 1];
    float cx = (lx - (float)(x * 8 + 4)) * inv;
    float cy = (ly - (float)(y * 8 + 4)) * inv;

    // issue first bases loads early so latency hides under the offsets FMAs
    const float* bp = bases_full + pc;
    float q0 = bp[0], q1 = bp[HW], q2 = bp[2 * (size_t)HW], q3 = bp[3 * (size_t)HW];

    // ---- layer 0: h = relu(W0 x + b0), c-outer streaming, packed pairs ----
    v2f h2[16];
    {
        const v2f* br  = (const v2f*)(wn + TB0);
        const v2f* w0r = (const v2f*)(wn + TW0);
        const v2f* w1r = (const v2f*)(wn + TW0 + 32);
        v2f cx2 = cx, cy2 = cy;
        #pragma unroll
        for (int g = 0; g < 16; g++)
            h2[g] = br[g] + w0r[g] * cx2 + w1r[g] * cy2;
    }
    // 4-deep rolling prefetch over the 32 bases channels
    #pragma unroll 2
    for (int c0 = 0; c0 < 32; c0 += 4) {
        float n0 = 0.f, n1 = 0.f, n2 = 0.f, n3 = 0.f;
        if (c0 + 4 < 32) {
            n0 = bp[(size_t)(c0 + 4) * HW];
            n1 = bp[(size_t)(c0 + 5) * HW];
            n2 = bp[(size_t)(c0 + 6) * HW];
            n3 = bp[(size_t)(c0 + 7) * HW];
        }
        float qq[4] = {q0, q1, q2, q3};
        #pragma unroll
        for (int u = 0; u < 4; u++) {
            v2f bv2 = qq[u];
            const v2f* wr = (const v2f*)(wn + TW0 + (c0 + u + 2) * 32);
            #pragma unroll
            for (int g = 0; g < 16; g++)
                h2[g] += wr[g] * bv2;
        }
        q0 = n0; q1 = n1; q2 = n2; q3 = n3;
    }
    #pragma unroll
    for (int g = 0; g < 16; g++) {
        h2[g].x = fmaxf(h2[g].x, 0.0f);
        h2[g].y = fmaxf(h2[g].y, 0.0f);
    }

    // ---- layer 1: packed pairs, scalar-broadcast activations ----
    v2f g2[16];
    {
        const v2f* br = (const v2f*)(wn + TB1);
        #pragma unroll
        for (int g = 0; g < 16; g++) g2[g] = br[g];
    }
    #pragma unroll 4
    for (int c = 0; c < 32; c++) {
        v2f xv2 = (c & 1) ? h2[c >> 1].y : h2[c >> 1].x;
        const v2f* wr = (const v2f*)(wn + TW1 + c * 32);
        #pragma unroll
        for (int g = 0; g < 16; g++)
            g2[g] += wr[g] * xv2;
    }
    #pragma unroll
    for (int g = 0; g < 16; g++) {
        g2[g].x = fmaxf(g2[g].x, 0.0f);
        g2[g].y = fmaxf(g2[g].y, 0.0f);
    }

    // ---- layer 2: packed dot products; store logits + LDS stage-1 write ----
    size_t obase = (size_t)n * NKP * HW;
    #pragma unroll
    for (int k = 0; k < NKP; k++) {
        const v2f* wr = (const v2f*)(wn + TW2 + k * 32);
        v2f s2 = wr[0] * g2[0];
        #pragma unroll
        for (int g = 1; g < 16; g++)
            s2 += wr[g] * g2[g];
        float s = wn[TB2 + k] + s2.x + s2.y;
        if (valid)
            __builtin_nontemporal_store(s, &out_logits[obase + (size_t)k * HW + p0]);
        smax[k][tid] = valid ? s : -__builtin_inff();
    }
    __syncthreads();

    // ---- stage 2a: 17 k's x 30 strands, ascending-index strict-> scan ----
    if (tid < 510) {
        int k = tid / 30, j = tid % 30;
        float bv = -__builtin_inff();
        int bi = 0;
        for (int i = j; i < 512; i += 30) {
            float v = smax[k][i];
            if (v > bv) { bv = v; bi = i; }
        }
        unsigned pix = (unsigned)(bx * PXB + bi);
        cand[k][j] = ((unsigned long long)mono_f32(bv) << 32) |
                     (unsigned long long)(0xFFFFFFFFu - pix);
    }
    __syncthreads();

    // ---- stage 2b: 17 threads reduce 30 candidates each ----
    if (tid < NKP) {
        unsigned long long m = cand[tid][0];
        #pragma unroll
        for (int j = 1; j < 30; j++)
            if (cand[tid][j] > m) m = cand[tid][j];
        partial[((size_t)n * NKP + tid) * NBX + bx] = m;
    }
}

// ========== kernel 4: final argmax reduce + keypoint ==========
__global__ __launch_bounds__(64) void kp_final(const unsigned long long* __restrict__ partial,
                                               const float* __restrict__ bases_full,
                                               float* __restrict__ kp_out) {
    int b = blockIdx.x;
    int n = b / NKP, k = b % NKP;
    int lane = threadIdx.x;
    unsigned long long v = (lane < NBX) ? partial[((size_t)n * NKP + k) * NBX + lane] : 0ull;
    #pragma unroll
    for (int off = 32; off > 0; off >>= 1) {
        unsigned long long o = __shfl_down(v, off);
        if (o > v) v = o;
    }
    if (lane == 0) {
        int p = (int)(0xFFFFFFFFu - (unsigned)(v & 0xFFFFFFFFull));
        int yy = p / WDIM;
        int xx = p - yy * WDIM;
        float kx = bases_full[(size_t)(NBASES + 2 * k) * HW + p] + (float)(xx * 8 + 4);
        float ky = bases_full[(size_t)(NBASES + 2 * k + 1) * HW + p] + (float)(yy * 8 + 4);
        kp_out[((size_t)n * NKP + k) * 2 + 0] = kx;
        kp_out[((size_t)n * NKP + k) * 2 + 1] = ky;
    }
}

extern "C" void kernel_launch(void* const* d_in, const int* in_sizes, int n_in,
                              void* d_out, int out_size, void* d_ws, size_t ws_size,
                              hipStream_t stream) {
    const float* bases_full = (const float*)d_in[0];
    const float* top_feats  = (const float*)d_in[1];
    const float* locations  = (const float*)d_in[2];
    const float* atten_W    = (const float*)d_in[3];
    const float* atten_b    = (const float*)d_in[4];
    const float* soi        = (const float*)d_in[5];
    const int*   fpn        = (const int*)d_in[6];
    float* out   = (float*)d_out;
    float* att_p = (float*)((char*)d_ws + ATT_OFF);
    unsigned long long* argp = (unsigned long long*)((char*)d_ws + ARGP_OFF);
    float* gemmp = (float*)((char*)d_ws + GEMMP_OFF);

    gemm_attn<<<NJT * KSPLIT, 256, 0, stream>>>(top_feats, atten_W, gemmp);

    dim3 gr((AL + 255) / 256, NI);   // 11 x 64
    reduce_attn<<<gr, 256, 0, stream>>>(gemmp, atten_b, att_p);

    dim3 g2(NBX, NI);   // 30 x 64
    pixel_head<<<g2, 512, 0, stream>>>(bases_full, att_p, locations, soi, fpn, out, argp);

    float* kp_out = out + (size_t)NI * NKP * HW;
    kp_final<<<NI * NKP, 64, 0, stream>>>(argp, bases_full, kp_out);
}